// Round 18
// baseline (58.965 us; speedup 1.0000x reference)
//
#include <hip/hip_runtime.h>
#include <hip/hip_bf16.h>

// GNN layer: out = segment_sum(feat[src], dst) @ W^T + b
// Round 18: r17 tile-major structure +
//   - cvt via __float22bfloat162_rn (v_cvt_pk_bf16_f32; r17's manual f2bf
//     bit-twiddle was ~4 VALU ops/element, ~320 inst/lane in transform)
//   - PART_T 8192 -> 4096 (245 partition blocks; halves each block's serial
//     LDS-atomic pole, same total work)
// Pipeline: prep (partition tiles front-clustered | MFMA transform) ->
// slab_gather (assemble per-tile runs, LDS counting-sort, owner-computes
// gather 8-lane x uint4, + bias).

#define DIM 64
#define SLAB_SHIFT 6
#define SLAB_NODES 64
#define MAX_SLABS 1600    // >= ceil(100000/64) = 1563
#define SLAB_CAP 1024     // gather staging capacity (avg 640, +20 sigma)
#define PART_T 4096       // edges per partition tile (245 tiles)
#define MAX_TILES 256     // >= ceil(1e6/4096) = 245

typedef __attribute__((ext_vector_type(8))) short bf16x8;
typedef __attribute__((ext_vector_type(4))) float f32x4;

__device__ __forceinline__ float bf2f(unsigned short h) {
    return __uint_as_float((unsigned)h << 16);
}
// Load 8 consecutive f32 -> bf16x8 fragment via packed-convert.
__device__ __forceinline__ bf16x8 cvt8(const float* p) {
    float4 x = *(const float4*)p;
    float4 y = *(const float4*)(p + 4);
    union { bf16x8 v; __hip_bfloat162 h[4]; } u;
    u.h[0] = __float22bfloat162_rn({x.x, x.y});
    u.h[1] = __float22bfloat162_rn({x.z, x.w});
    u.h[2] = __float22bfloat162_rn({y.x, y.y});
    u.h[3] = __float22bfloat162_rn({y.z, y.w});
    return u.v;
}

// Fat kernel: partition (blocks < ntiles) / MFMA transform (blocks >= ntiles).
__global__ void __launch_bounds__(256, 4)
prep_kernel(const float* __restrict__ feat, const float* __restrict__ W,
            unsigned short* __restrict__ g,
            const int* __restrict__ src, const int* __restrict__ dst,
            unsigned int* __restrict__ meta, unsigned int* __restrict__ packed,
            int n_nodes, int n_edges, int ntiles) {
    __shared__ int cnt[MAX_SLABS];
    __shared__ int offs[MAX_SLABS];
    __shared__ int wsum[4];
    int tid = threadIdx.x;

    if (blockIdx.x < ntiles) {
        // ---------- partition: one 4096-edge tile, tile-major ----------
        int tile = blockIdx.x;
        int t0 = tile * PART_T;
        int m = min(PART_T, n_edges - t0);
        int m4 = m >> 2;
        int nslab = (n_nodes + SLAB_NODES - 1) / SLAB_NODES;
        for (int i = tid; i < nslab; i += 256) cnt[i] = 0;
        __syncthreads();
        // phase A: count
        const int4* d4 = (const int4*)(dst + t0);
        for (int i = tid; i < m4; i += 256) {
            int4 d = d4[i];
            atomicAdd(&cnt[d.x >> SLAB_SHIFT], 1);
            atomicAdd(&cnt[d.y >> SLAB_SHIFT], 1);
            atomicAdd(&cnt[d.z >> SLAB_SHIFT], 1);
            atomicAdd(&cnt[d.w >> SLAB_SHIFT], 1);
        }
        if (tid < (m & 3)) atomicAdd(&cnt[dst[t0 + (m4 << 2) + tid] >> SLAB_SHIFT], 1);
        __syncthreads();
        // phase B: block-exclusive scan of nslab counts (7 bins/thread).
        int tbase = tid * 7;
        int loc[7];
        int lsum = 0;
#pragma unroll
        for (int j = 0; j < 7; ++j) {
            int bin = tbase + j;
            int c = (bin < nslab) ? cnt[bin] : 0;
            loc[j] = lsum;
            lsum += c;
        }
        int lane = tid & 63, wv = tid >> 6;
        int incl = lsum;
#pragma unroll
        for (int o = 1; o < 64; o <<= 1) {
            int x = __shfl_up(incl, o, 64);
            if (lane >= o) incl += x;
        }
        if (lane == 63) wsum[wv] = incl;
        __syncthreads();
        int woff = 0;
        for (int k = 0; k < wv; ++k) woff += wsum[k];
        int base = woff + incl - lsum;       // block-exclusive thread base
        unsigned int* mrow = meta + (long)tile * nslab;
#pragma unroll
        for (int j = 0; j < 7; ++j) {
            int bin = tbase + j;
            if (bin < nslab) {
                int c = cnt[bin];
                int o = base + loc[j];
                mrow[bin] = ((unsigned)o << 16) | (unsigned)c;
                offs[bin] = o;               // running cursor for phase C
            }
        }
        __syncthreads();
        // phase C: scatter into OWN tile region (no global atomics).
        const int4* s4 = (const int4*)(src + t0);
        unsigned int* preg = packed + (long)tile * PART_T;
        for (int i = tid; i < m4; i += 256) {
            int4 d = d4[i];
            int4 s = s4[i];
            int sl, p;
            sl = d.x >> SLAB_SHIFT; p = atomicAdd(&offs[sl], 1);
            preg[p] = ((unsigned)(d.x & (SLAB_NODES - 1)) << 25) | (unsigned)s.x;
            sl = d.y >> SLAB_SHIFT; p = atomicAdd(&offs[sl], 1);
            preg[p] = ((unsigned)(d.y & (SLAB_NODES - 1)) << 25) | (unsigned)s.y;
            sl = d.z >> SLAB_SHIFT; p = atomicAdd(&offs[sl], 1);
            preg[p] = ((unsigned)(d.z & (SLAB_NODES - 1)) << 25) | (unsigned)s.z;
            sl = d.w >> SLAB_SHIFT; p = atomicAdd(&offs[sl], 1);
            preg[p] = ((unsigned)(d.w & (SLAB_NODES - 1)) << 25) | (unsigned)s.w;
        }
        if (tid < (m & 3)) {
            int e = t0 + (m4 << 2) + tid;
            int d = dst[e];
            int sl = d >> SLAB_SHIFT;
            int p = atomicAdd(&offs[sl], 1);
            preg[p] = ((unsigned)(d & (SLAB_NODES - 1)) << 25) | (unsigned)src[e];
        }
    } else {
        // -------- transform: 64 rows per block, MFMA, no LDS --------
        // A = W rows (m = output col o), B = feat rows (n = node).
        // D frag: n(node)=lane&15, m(o)=(lane>>4)*4+reg -> ushort4 stores.
        int ttile = blockIdx.x - ntiles;
        int lane = tid & 63;
        int wv2 = tid >> 6;
        int base_node = ttile * 64 + wv2 * 16;
        int rl = lane & 15;
        int kb = (lane >> 4) * 8;

        int node = base_node + rl;
        bf16x8 bLo, bHi;
        if (node < n_nodes) {
            const float* fr = feat + (long)node * DIM;
            bLo = cvt8(fr + kb);
            bHi = cvt8(fr + kb + 32);
        } else {
            bf16x8 z = {0, 0, 0, 0, 0, 0, 0, 0};
            bLo = z; bHi = z;
        }

        unsigned short* gp = g + (long)node * DIM + (lane >> 4) * 4;
#pragma unroll
        for (int t = 0; t < 4; ++t) {
            const float* wr = W + (long)(t * 16 + rl) * DIM;
            bf16x8 aLo = cvt8(wr + kb);
            bf16x8 aHi = cvt8(wr + kb + 32);
            f32x4 c = {0.f, 0.f, 0.f, 0.f};
            c = __builtin_amdgcn_mfma_f32_16x16x32_bf16(aLo, bLo, c, 0, 0, 0);
            c = __builtin_amdgcn_mfma_f32_16x16x32_bf16(aHi, bHi, c, 0, 0, 0);
            if (node < n_nodes) {
                union { ushort4 s; __hip_bfloat162 h[2]; } o4;
                o4.h[0] = __float22bfloat162_rn({c[0], c[1]});
                o4.h[1] = __float22bfloat162_rn({c[2], c[3]});
                *(ushort4*)(gp + t * 16) = o4.s;
            }
        }
    }
}

// One block per 64-node slab.  Assemble the slab's edges from per-tile runs
// (meta), then LDS counting-sort by exact dst (shfl scan) + owner-computes
// gather (8-lane groups, uint4 = 8 bf16/lane, unroll 4), + bias.
__global__ void __launch_bounds__(512, 8)
slab_gather(const unsigned short* __restrict__ g,
            const unsigned int* __restrict__ meta,
            const unsigned int* __restrict__ packed,
            const float* __restrict__ b, float* __restrict__ out,
            int n_nodes, int ntiles, int nslab) {
    __shared__ unsigned int raw[SLAB_CAP];
    __shared__ int srt[SLAB_CAP];
    __shared__ int cnt[SLAB_NODES];
    __shared__ int lstarts[SLAB_NODES + 1];
    __shared__ int sc[MAX_TILES];
    __shared__ int runDst[MAX_TILES];
    __shared__ int runSrc[MAX_TILES];
    __shared__ int runCnt[MAX_TILES];
    __shared__ int ceS;
    int tid = threadIdx.x;
    int slab = blockIdx.x;

    // phase 1: read per-tile meta, scan run lengths.
    int c_t = 0, o_t = 0;
    if (tid < ntiles) {
        unsigned int mt = meta[(long)tid * nslab + slab];
        c_t = (int)(mt & 0xFFFFu);
        o_t = (int)(mt >> 16);
    }
    if (tid < MAX_TILES) sc[tid] = c_t;      // zero beyond ntiles (c_t=0)
    __syncthreads();
    for (int off = 1; off < MAX_TILES; off <<= 1) {
        int x = 0;
        if (tid < MAX_TILES && tid >= off) x = sc[tid - off];
        __syncthreads();
        if (tid < MAX_TILES) sc[tid] += x;
        __syncthreads();
    }
    if (tid < ntiles) {
        runDst[tid] = sc[tid] - c_t;         // exclusive
        runSrc[tid] = tid * PART_T + o_t;
        runCnt[tid] = c_t;
    }
    if (tid == 0) ceS = min(sc[MAX_TILES - 1], SLAB_CAP);
    if (tid < SLAB_NODES) cnt[tid] = 0;
    __syncthreads();
    int ce = ceS;

    // phase 2: copy runs into raw[] (2 lanes per tile).
    {
        int t = tid >> 1, j = tid & 1;
        if (t < ntiles) {
            int rc = runCnt[t], rd = runDst[t], rs = runSrc[t];
            for (int k = j; k < rc; k += 2) {
                int p = rd + k;
                if (p < SLAB_CAP) raw[p] = packed[rs + k];
            }
        }
    }
    __syncthreads();

    // phase 3: counting sort by exact dst-low.
    for (int k = tid; k < ce; k += 512) atomicAdd(&cnt[raw[k] >> 25], 1);
    __syncthreads();
    if (tid < 64) {
        int v = cnt[tid];
        int orig = v;
#pragma unroll
        for (int off = 1; off < 64; off <<= 1) {
            int x = __shfl_up(v, off, 64);
            v += (tid >= off) ? x : 0;
        }
        lstarts[tid + 1] = v;
        cnt[tid] = v - orig;
        if (tid == 0) lstarts[0] = 0;
    }
    __syncthreads();
    for (int k = tid; k < ce; k += 512) {
        unsigned int v = raw[k];
        int nl = (int)(v >> 25);
        int p = atomicAdd(&cnt[nl], 1);
        srt[p] = (int)(v & 0x1FFFFFFu);
    }
    __syncthreads();

    // phase 4: gather + bias + writeout.
    int grp = tid >> 3;      // 0..63: owns node `grp`
    int part = tid & 7;      // uint4 chunk (8 bf16 columns)
    int node0 = slab * SLAB_NODES;
    int nsn = min(SLAB_NODES, n_nodes - node0);
    const uint4* g4 = (const uint4*)g;

    if (grp < nsn) {
        float4 accA = *(const float4*)(b + part * 8);
        float4 accB = *(const float4*)(b + part * 8 + 4);
        int a0 = lstarts[grp], a1 = lstarts[grp + 1];
        int e = a0;
        for (; e + 3 < a1; e += 4) {
            uint4 v0 = g4[(long)srt[e]     * 8 + part];
            uint4 v1 = g4[(long)srt[e + 1] * 8 + part];
            uint4 v2 = g4[(long)srt[e + 2] * 8 + part];
            uint4 v3 = g4[(long)srt[e + 3] * 8 + part];
#define ACC8(v)                                                          \
            accA.x += bf2f((unsigned short)(v.x & 0xFFFF));              \
            accA.y += bf2f((unsigned short)(v.x >> 16));                 \
            accA.z += bf2f((unsigned short)(v.y & 0xFFFF));              \
            accA.w += bf2f((unsigned short)(v.y >> 16));                 \
            accB.x += bf2f((unsigned short)(v.z & 0xFFFF));              \
            accB.y += bf2f((unsigned short)(v.z >> 16));                 \
            accB.z += bf2f((unsigned short)(v.w & 0xFFFF));              \
            accB.w += bf2f((unsigned short)(v.w >> 16));
            ACC8(v0) ACC8(v1) ACC8(v2) ACC8(v3)
        }
        for (; e < a1; ++e) {
            uint4 v0 = g4[(long)srt[e] * 8 + part];
            ACC8(v0)
        }
#undef ACC8
        float* op = out + (long)(node0 + grp) * DIM + part * 8;
        *(float4*)op = accA;
        *(float4*)(op + 4) = accB;
    }
}

extern "C" void kernel_launch(void* const* d_in, const int* in_sizes, int n_in,
                              void* d_out, int out_size, void* d_ws, size_t ws_size,
                              hipStream_t stream) {
    const float* feat = (const float*)d_in[0];
    const int*   src  = (const int*)d_in[1];
    const int*   dst  = (const int*)d_in[2];
    const float* W    = (const float*)d_in[3];
    const float* b    = (const float*)d_in[4];
    float* out = (float*)d_out;

    int n_nodes = in_sizes[0] / DIM;
    int n_edges = in_sizes[1];
    int nslab = (n_nodes + SLAB_NODES - 1) / SLAB_NODES;   // 1563
    int ntiles = (n_edges + PART_T - 1) / PART_T;          // 245

    // workspace: g bf16 (12.8 MB), meta (1.53 MB), packed (4.03 MB)
    char* ws = (char*)d_ws;
    size_t off = 0;
    unsigned short* g = (unsigned short*)(ws + off);
    off += ((size_t)n_nodes * DIM * 2 + 255) & ~(size_t)255;
    unsigned int* meta = (unsigned int*)(ws + off);
    off += ((size_t)ntiles * nslab * 4 + 255) & ~(size_t)255;
    unsigned int* packed = (unsigned int*)(ws + off);      // ntiles*PART_T u32

    int tblocks = (n_nodes + 63) / 64;                     // 1563
    prep_kernel<<<ntiles + tblocks, 256, 0, stream>>>(
        feat, W, g, src, dst, meta, packed, n_nodes, n_edges, ntiles);
    slab_gather<<<nslab, 512, 0, stream>>>(g, meta, packed, b, out,
                                           n_nodes, ntiles, nslab);
}

// Round 19
// 51.353 us; speedup vs baseline: 1.1482x; 1.1482x over previous
//
#include <hip/hip_runtime.h>
#include <hip/hip_bf16.h>

// GNN layer: out = segment_sum(feat[src], dst) @ W^T + b
// Round 19 (prep-only changes; gather identical to r18 for attribution):
//   - transform: 256 rows/block (4 sub-tiles), W fragments hoisted to VGPRs
//     once per block (W L2 traffic and W-convert VALU /4; 391 blocks)
//   - partition: dst tile staged in LDS during count pass; scatter pass
//     reads it from LDS (saves the 4 MB global re-read)
// Pipeline: prep (partition | MFMA transform) -> slab_gather (per-tile run
// assembly, LDS counting-sort, owner-computes gather, + bias).

#define DIM 64
#define SLAB_SHIFT 6
#define SLAB_NODES 64
#define MAX_SLABS 1600    // >= ceil(100000/64) = 1563
#define SLAB_CAP 1024     // gather staging capacity (avg 640, +20 sigma)
#define PART_T 4096       // edges per partition tile (245 tiles)
#define MAX_TILES 256     // >= ceil(1e6/4096) = 245

typedef __attribute__((ext_vector_type(8))) short bf16x8;
typedef __attribute__((ext_vector_type(4))) float f32x4;

__device__ __forceinline__ float bf2f(unsigned short h) {
    return __uint_as_float((unsigned)h << 16);
}
// Load 8 consecutive f32 -> bf16x8 fragment via packed-convert.
__device__ __forceinline__ bf16x8 cvt8(const float* p) {
    float4 x = *(const float4*)p;
    float4 y = *(const float4*)(p + 4);
    union { bf16x8 v; __hip_bfloat162 h[4]; } u;
    u.h[0] = __float22bfloat162_rn({x.x, x.y});
    u.h[1] = __float22bfloat162_rn({x.z, x.w});
    u.h[2] = __float22bfloat162_rn({y.x, y.y});
    u.h[3] = __float22bfloat162_rn({y.z, y.w});
    return u.v;
}

// Fat kernel: partition (blocks < ntiles) / MFMA transform (blocks >= ntiles,
// 256 rows each).
__global__ void __launch_bounds__(256, 4)
prep_kernel(const float* __restrict__ feat, const float* __restrict__ W,
            unsigned short* __restrict__ g,
            const int* __restrict__ src, const int* __restrict__ dst,
            unsigned int* __restrict__ meta, unsigned int* __restrict__ packed,
            int n_nodes, int n_edges, int ntiles) {
    __shared__ int cnt[MAX_SLABS];
    __shared__ int offs[MAX_SLABS];
    __shared__ int dstbuf[PART_T];          // 16 KB: dst tile staged in LDS
    __shared__ int wsum[4];
    int tid = threadIdx.x;

    if (blockIdx.x < ntiles) {
        // ---------- partition: one 4096-edge tile, tile-major ----------
        int tile = blockIdx.x;
        int t0 = tile * PART_T;
        int m = min(PART_T, n_edges - t0);
        int m4 = m >> 2;
        int nslab = (n_nodes + SLAB_NODES - 1) / SLAB_NODES;
        for (int i = tid; i < nslab; i += 256) cnt[i] = 0;
        __syncthreads();
        // phase A: count + stage dst into LDS
        const int4* d4 = (const int4*)(dst + t0);
        for (int i = tid; i < m4; i += 256) {
            int4 d = d4[i];
            ((int4*)dstbuf)[i] = d;
            atomicAdd(&cnt[d.x >> SLAB_SHIFT], 1);
            atomicAdd(&cnt[d.y >> SLAB_SHIFT], 1);
            atomicAdd(&cnt[d.z >> SLAB_SHIFT], 1);
            atomicAdd(&cnt[d.w >> SLAB_SHIFT], 1);
        }
        if (tid < (m & 3)) {
            int d = dst[t0 + (m4 << 2) + tid];
            dstbuf[(m4 << 2) + tid] = d;
            atomicAdd(&cnt[d >> SLAB_SHIFT], 1);
        }
        __syncthreads();
        // phase B: block-exclusive scan of nslab counts (7 bins/thread).
        int tbase = tid * 7;
        int loc[7];
        int lsum = 0;
#pragma unroll
        for (int j = 0; j < 7; ++j) {
            int bin = tbase + j;
            int c = (bin < nslab) ? cnt[bin] : 0;
            loc[j] = lsum;
            lsum += c;
        }
        int lane = tid & 63, wv = tid >> 6;
        int incl = lsum;
#pragma unroll
        for (int o = 1; o < 64; o <<= 1) {
            int x = __shfl_up(incl, o, 64);
            if (lane >= o) incl += x;
        }
        if (lane == 63) wsum[wv] = incl;
        __syncthreads();
        int woff = 0;
        for (int k = 0; k < wv; ++k) woff += wsum[k];
        int base = woff + incl - lsum;       // block-exclusive thread base
        unsigned int* mrow = meta + (long)tile * nslab;
#pragma unroll
        for (int j = 0; j < 7; ++j) {
            int bin = tbase + j;
            if (bin < nslab) {
                int c = cnt[bin];
                int o = base + loc[j];
                mrow[bin] = ((unsigned)o << 16) | (unsigned)c;
                offs[bin] = o;               // running cursor for phase C
            }
        }
        __syncthreads();
        // phase C: scatter into OWN tile region (dst from LDS, src global).
        const int4* s4 = (const int4*)(src + t0);
        unsigned int* preg = packed + (long)tile * PART_T;
        for (int i = tid; i < m4; i += 256) {
            int4 d = ((const int4*)dstbuf)[i];
            int4 s = s4[i];
            int sl, p;
            sl = d.x >> SLAB_SHIFT; p = atomicAdd(&offs[sl], 1);
            preg[p] = ((unsigned)(d.x & (SLAB_NODES - 1)) << 25) | (unsigned)s.x;
            sl = d.y >> SLAB_SHIFT; p = atomicAdd(&offs[sl], 1);
            preg[p] = ((unsigned)(d.y & (SLAB_NODES - 1)) << 25) | (unsigned)s.y;
            sl = d.z >> SLAB_SHIFT; p = atomicAdd(&offs[sl], 1);
            preg[p] = ((unsigned)(d.z & (SLAB_NODES - 1)) << 25) | (unsigned)s.z;
            sl = d.w >> SLAB_SHIFT; p = atomicAdd(&offs[sl], 1);
            preg[p] = ((unsigned)(d.w & (SLAB_NODES - 1)) << 25) | (unsigned)s.w;
        }
        if (tid < (m & 3)) {
            int e = (m4 << 2) + tid;
            int d = dstbuf[e];
            int sl = d >> SLAB_SHIFT;
            int p = atomicAdd(&offs[sl], 1);
            preg[p] = ((unsigned)(d & (SLAB_NODES - 1)) << 25) | (unsigned)src[t0 + e];
        }
    } else {
        // ------ transform: 256 rows per block, W frags hoisted ------
        // A = W rows (m = output col o), B = feat rows (n = node).
        // D frag: n(node)=lane&15, m(o)=(lane>>4)*4+reg -> ushort4 stores.
        int ttile = blockIdx.x - ntiles;
        int lane = tid & 63;
        int wv2 = tid >> 6;
        int rl = lane & 15;
        int kb = (lane >> 4) * 8;

        bf16x8 wa[4][2];                 // W fragments, loaded once
#pragma unroll
        for (int t = 0; t < 4; ++t) {
            const float* wr = W + (long)(t * 16 + rl) * DIM;
            wa[t][0] = cvt8(wr + kb);
            wa[t][1] = cvt8(wr + kb + 32);
        }

#pragma unroll
        for (int sub = 0; sub < 4; ++sub) {
            int node = ttile * 256 + sub * 64 + wv2 * 16 + rl;
            bf16x8 bLo, bHi;
            if (node < n_nodes) {
                const float* fr = feat + (long)node * DIM;
                bLo = cvt8(fr + kb);
                bHi = cvt8(fr + kb + 32);
            } else {
                bf16x8 z = {0, 0, 0, 0, 0, 0, 0, 0};
                bLo = z; bHi = z;
            }
            unsigned short* gp = g + (long)node * DIM + (lane >> 4) * 4;
#pragma unroll
            for (int t = 0; t < 4; ++t) {
                f32x4 c = {0.f, 0.f, 0.f, 0.f};
                c = __builtin_amdgcn_mfma_f32_16x16x32_bf16(wa[t][0], bLo, c, 0, 0, 0);
                c = __builtin_amdgcn_mfma_f32_16x16x32_bf16(wa[t][1], bHi, c, 0, 0, 0);
                if (node < n_nodes) {
                    union { ushort4 s; __hip_bfloat162 h[2]; } o4;
                    o4.h[0] = __float22bfloat162_rn({c[0], c[1]});
                    o4.h[1] = __float22bfloat162_rn({c[2], c[3]});
                    *(ushort4*)(gp + t * 16) = o4.s;
                }
            }
        }
    }
}

// One block per 64-node slab.  Assemble the slab's edges from per-tile runs
// (meta), then LDS counting-sort by exact dst (shfl scan) + owner-computes
// gather (8-lane groups, uint4 = 8 bf16/lane, unroll 4), + bias.
__global__ void __launch_bounds__(512, 8)
slab_gather(const unsigned short* __restrict__ g,
            const unsigned int* __restrict__ meta,
            const unsigned int* __restrict__ packed,
            const float* __restrict__ b, float* __restrict__ out,
            int n_nodes, int ntiles, int nslab) {
    __shared__ unsigned int raw[SLAB_CAP];
    __shared__ int srt[SLAB_CAP];
    __shared__ int cnt[SLAB_NODES];
    __shared__ int lstarts[SLAB_NODES + 1];
    __shared__ int sc[MAX_TILES];
    __shared__ int runDst[MAX_TILES];
    __shared__ int runSrc[MAX_TILES];
    __shared__ int runCnt[MAX_TILES];
    __shared__ int ceS;
    int tid = threadIdx.x;
    int slab = blockIdx.x;

    // phase 1: read per-tile meta, scan run lengths.
    int c_t = 0, o_t = 0;
    if (tid < ntiles) {
        unsigned int mt = meta[(long)tid * nslab + slab];
        c_t = (int)(mt & 0xFFFFu);
        o_t = (int)(mt >> 16);
    }
    if (tid < MAX_TILES) sc[tid] = c_t;      // zero beyond ntiles (c_t=0)
    __syncthreads();
    for (int off = 1; off < MAX_TILES; off <<= 1) {
        int x = 0;
        if (tid < MAX_TILES && tid >= off) x = sc[tid - off];
        __syncthreads();
        if (tid < MAX_TILES) sc[tid] += x;
        __syncthreads();
    }
    if (tid < ntiles) {
        runDst[tid] = sc[tid] - c_t;         // exclusive
        runSrc[tid] = tid * PART_T + o_t;
        runCnt[tid] = c_t;
    }
    if (tid == 0) ceS = min(sc[MAX_TILES - 1], SLAB_CAP);
    if (tid < SLAB_NODES) cnt[tid] = 0;
    __syncthreads();
    int ce = ceS;

    // phase 2: copy runs into raw[] (2 lanes per tile).
    {
        int t = tid >> 1, j = tid & 1;
        if (t < ntiles) {
            int rc = runCnt[t], rd = runDst[t], rs = runSrc[t];
            for (int k = j; k < rc; k += 2) {
                int p = rd + k;
                if (p < SLAB_CAP) raw[p] = packed[rs + k];
            }
        }
    }
    __syncthreads();

    // phase 3: counting sort by exact dst-low.
    for (int k = tid; k < ce; k += 512) atomicAdd(&cnt[raw[k] >> 25], 1);
    __syncthreads();
    if (tid < 64) {
        int v = cnt[tid];
        int orig = v;
#pragma unroll
        for (int off = 1; off < 64; off <<= 1) {
            int x = __shfl_up(v, off, 64);
            v += (tid >= off) ? x : 0;
        }
        lstarts[tid + 1] = v;
        cnt[tid] = v - orig;
        if (tid == 0) lstarts[0] = 0;
    }
    __syncthreads();
    for (int k = tid; k < ce; k += 512) {
        unsigned int v = raw[k];
        int nl = (int)(v >> 25);
        int p = atomicAdd(&cnt[nl], 1);
        srt[p] = (int)(v & 0x1FFFFFFu);
    }
    __syncthreads();

    // phase 4: gather + bias + writeout.
    int grp = tid >> 3;      // 0..63: owns node `grp`
    int part = tid & 7;      // uint4 chunk (8 bf16 columns)
    int node0 = slab * SLAB_NODES;
    int nsn = min(SLAB_NODES, n_nodes - node0);
    const uint4* g4 = (const uint4*)g;

    if (grp < nsn) {
        float4 accA = *(const float4*)(b + part * 8);
        float4 accB = *(const float4*)(b + part * 8 + 4);
        int a0 = lstarts[grp], a1 = lstarts[grp + 1];
        int e = a0;
        for (; e + 3 < a1; e += 4) {
            uint4 v0 = g4[(long)srt[e]     * 8 + part];
            uint4 v1 = g4[(long)srt[e + 1] * 8 + part];
            uint4 v2 = g4[(long)srt[e + 2] * 8 + part];
            uint4 v3 = g4[(long)srt[e + 3] * 8 + part];
#define ACC8(v)                                                          \
            accA.x += bf2f((unsigned short)(v.x & 0xFFFF));              \
            accA.y += bf2f((unsigned short)(v.x >> 16));                 \
            accA.z += bf2f((unsigned short)(v.y & 0xFFFF));              \
            accA.w += bf2f((unsigned short)(v.y >> 16));                 \
            accB.x += bf2f((unsigned short)(v.z & 0xFFFF));              \
            accB.y += bf2f((unsigned short)(v.z >> 16));                 \
            accB.z += bf2f((unsigned short)(v.w & 0xFFFF));              \
            accB.w += bf2f((unsigned short)(v.w >> 16));
            ACC8(v0) ACC8(v1) ACC8(v2) ACC8(v3)
        }
        for (; e < a1; ++e) {
            uint4 v0 = g4[(long)srt[e] * 8 + part];
            ACC8(v0)
        }
#undef ACC8
        float* op = out + (long)(node0 + grp) * DIM + part * 8;
        *(float4*)op = accA;
        *(float4*)(op + 4) = accB;
    }
}

extern "C" void kernel_launch(void* const* d_in, const int* in_sizes, int n_in,
                              void* d_out, int out_size, void* d_ws, size_t ws_size,
                              hipStream_t stream) {
    const float* feat = (const float*)d_in[0];
    const int*   src  = (const int*)d_in[1];
    const int*   dst  = (const int*)d_in[2];
    const float* W    = (const float*)d_in[3];
    const float* b    = (const float*)d_in[4];
    float* out = (float*)d_out;

    int n_nodes = in_sizes[0] / DIM;
    int n_edges = in_sizes[1];
    int nslab = (n_nodes + SLAB_NODES - 1) / SLAB_NODES;   // 1563
    int ntiles = (n_edges + PART_T - 1) / PART_T;          // 245

    // workspace: g bf16 (12.8 MB), meta (1.53 MB), packed (4.03 MB)
    char* ws = (char*)d_ws;
    size_t off = 0;
    unsigned short* g = (unsigned short*)(ws + off);
    off += ((size_t)n_nodes * DIM * 2 + 255) & ~(size_t)255;
    unsigned int* meta = (unsigned int*)(ws + off);
    off += ((size_t)ntiles * nslab * 4 + 255) & ~(size_t)255;
    unsigned int* packed = (unsigned int*)(ws + off);      // ntiles*PART_T u32

    int tblocks = (n_nodes + 255) / 256;                   // 391
    prep_kernel<<<ntiles + tblocks, 256, 0, stream>>>(
        feat, W, g, src, dst, meta, packed, n_nodes, n_edges, ntiles);
    slab_gather<<<nslab, 512, 0, stream>>>(g, meta, packed, b, out,
                                           n_nodes, ntiles, nslab);
}

// Round 20
// 48.584 us; speedup vs baseline: 1.2137x; 1.0570x over previous
//
#include <hip/hip_runtime.h>
#include <hip/hip_bf16.h>

// GNN layer: out = segment_sum(feat[src], dst) @ W^T + b
// Round 20 (vs r19):
//   - gather phase 2: balanced binary-search run copy (was 2 lanes/tile with
//     Poisson-tail imbalance; now each element finds its tile via 8-step
//     search over the LDS scan, fully even across 512 threads)
//   - transform: 512 rows/block (8 sub-tiles, 196 blocks; W fragments
//     converted once per block, amortized 2x more)
// Pipeline: prep (partition tiles | MFMA transform) -> slab_gather
// (meta scan, balanced run assembly, LDS counting-sort, owner-computes
// gather 8-lane x uint4, + bias).

#define DIM 64
#define SLAB_SHIFT 6
#define SLAB_NODES 64
#define MAX_SLABS 1600    // >= ceil(100000/64) = 1563
#define SLAB_CAP 1024     // gather staging capacity (avg 640, +20 sigma)
#define PART_T 4096       // edges per partition tile (245 tiles)
#define MAX_TILES 256     // >= ceil(1e6/4096) = 245
#define TROWS 512         // transform rows per block

typedef __attribute__((ext_vector_type(8))) short bf16x8;
typedef __attribute__((ext_vector_type(4))) float f32x4;

__device__ __forceinline__ float bf2f(unsigned short h) {
    return __uint_as_float((unsigned)h << 16);
}
// Load 8 consecutive f32 -> bf16x8 fragment via packed-convert.
__device__ __forceinline__ bf16x8 cvt8(const float* p) {
    float4 x = *(const float4*)p;
    float4 y = *(const float4*)(p + 4);
    union { bf16x8 v; __hip_bfloat162 h[4]; } u;
    u.h[0] = __float22bfloat162_rn({x.x, x.y});
    u.h[1] = __float22bfloat162_rn({x.z, x.w});
    u.h[2] = __float22bfloat162_rn({y.x, y.y});
    u.h[3] = __float22bfloat162_rn({y.z, y.w});
    return u.v;
}

// Fat kernel: partition (blocks < ntiles) / MFMA transform (blocks >= ntiles,
// TROWS rows each).
__global__ void __launch_bounds__(256, 4)
prep_kernel(const float* __restrict__ feat, const float* __restrict__ W,
            unsigned short* __restrict__ g,
            const int* __restrict__ src, const int* __restrict__ dst,
            unsigned int* __restrict__ meta, unsigned int* __restrict__ packed,
            int n_nodes, int n_edges, int ntiles) {
    __shared__ int cnt[MAX_SLABS];
    __shared__ int offs[MAX_SLABS];
    __shared__ int dstbuf[PART_T];          // 16 KB: dst tile staged in LDS
    __shared__ int wsum[4];
    int tid = threadIdx.x;

    if (blockIdx.x < ntiles) {
        // ---------- partition: one 4096-edge tile, tile-major ----------
        int tile = blockIdx.x;
        int t0 = tile * PART_T;
        int m = min(PART_T, n_edges - t0);
        int m4 = m >> 2;
        int nslab = (n_nodes + SLAB_NODES - 1) / SLAB_NODES;
        for (int i = tid; i < nslab; i += 256) cnt[i] = 0;
        __syncthreads();
        // phase A: count + stage dst into LDS
        const int4* d4 = (const int4*)(dst + t0);
        for (int i = tid; i < m4; i += 256) {
            int4 d = d4[i];
            ((int4*)dstbuf)[i] = d;
            atomicAdd(&cnt[d.x >> SLAB_SHIFT], 1);
            atomicAdd(&cnt[d.y >> SLAB_SHIFT], 1);
            atomicAdd(&cnt[d.z >> SLAB_SHIFT], 1);
            atomicAdd(&cnt[d.w >> SLAB_SHIFT], 1);
        }
        if (tid < (m & 3)) {
            int d = dst[t0 + (m4 << 2) + tid];
            dstbuf[(m4 << 2) + tid] = d;
            atomicAdd(&cnt[d >> SLAB_SHIFT], 1);
        }
        __syncthreads();
        // phase B: block-exclusive scan of nslab counts (7 bins/thread).
        int tbase = tid * 7;
        int loc[7];
        int lsum = 0;
#pragma unroll
        for (int j = 0; j < 7; ++j) {
            int bin = tbase + j;
            int c = (bin < nslab) ? cnt[bin] : 0;
            loc[j] = lsum;
            lsum += c;
        }
        int lane = tid & 63, wv = tid >> 6;
        int incl = lsum;
#pragma unroll
        for (int o = 1; o < 64; o <<= 1) {
            int x = __shfl_up(incl, o, 64);
            if (lane >= o) incl += x;
        }
        if (lane == 63) wsum[wv] = incl;
        __syncthreads();
        int woff = 0;
        for (int k = 0; k < wv; ++k) woff += wsum[k];
        int base = woff + incl - lsum;       // block-exclusive thread base
        unsigned int* mrow = meta + (long)tile * nslab;
#pragma unroll
        for (int j = 0; j < 7; ++j) {
            int bin = tbase + j;
            if (bin < nslab) {
                int c = cnt[bin];
                int o = base + loc[j];
                mrow[bin] = ((unsigned)o << 16) | (unsigned)c;
                offs[bin] = o;               // running cursor for phase C
            }
        }
        __syncthreads();
        // phase C: scatter into OWN tile region (dst from LDS, src global).
        const int4* s4 = (const int4*)(src + t0);
        unsigned int* preg = packed + (long)tile * PART_T;
        for (int i = tid; i < m4; i += 256) {
            int4 d = ((const int4*)dstbuf)[i];
            int4 s = s4[i];
            int sl, p;
            sl = d.x >> SLAB_SHIFT; p = atomicAdd(&offs[sl], 1);
            preg[p] = ((unsigned)(d.x & (SLAB_NODES - 1)) << 25) | (unsigned)s.x;
            sl = d.y >> SLAB_SHIFT; p = atomicAdd(&offs[sl], 1);
            preg[p] = ((unsigned)(d.y & (SLAB_NODES - 1)) << 25) | (unsigned)s.y;
            sl = d.z >> SLAB_SHIFT; p = atomicAdd(&offs[sl], 1);
            preg[p] = ((unsigned)(d.z & (SLAB_NODES - 1)) << 25) | (unsigned)s.z;
            sl = d.w >> SLAB_SHIFT; p = atomicAdd(&offs[sl], 1);
            preg[p] = ((unsigned)(d.w & (SLAB_NODES - 1)) << 25) | (unsigned)s.w;
        }
        if (tid < (m & 3)) {
            int e = (m4 << 2) + tid;
            int d = dstbuf[e];
            int sl = d >> SLAB_SHIFT;
            int p = atomicAdd(&offs[sl], 1);
            preg[p] = ((unsigned)(d & (SLAB_NODES - 1)) << 25) | (unsigned)src[t0 + e];
        }
    } else {
        // ------ transform: TROWS rows per block, W frags hoisted ------
        // A = W rows (m = output col o), B = feat rows (n = node).
        // D frag: n(node)=lane&15, m(o)=(lane>>4)*4+reg -> ushort4 stores.
        int ttile = blockIdx.x - ntiles;
        int lane = tid & 63;
        int wv2 = tid >> 6;
        int rl = lane & 15;
        int kb = (lane >> 4) * 8;

        bf16x8 wa[4][2];                 // W fragments, loaded once
#pragma unroll
        for (int t = 0; t < 4; ++t) {
            const float* wr = W + (long)(t * 16 + rl) * DIM;
            wa[t][0] = cvt8(wr + kb);
            wa[t][1] = cvt8(wr + kb + 32);
        }

#pragma unroll
        for (int sub = 0; sub < TROWS / 64; ++sub) {
            int node = ttile * TROWS + sub * 64 + wv2 * 16 + rl;
            bf16x8 bLo, bHi;
            if (node < n_nodes) {
                const float* fr = feat + (long)node * DIM;
                bLo = cvt8(fr + kb);
                bHi = cvt8(fr + kb + 32);
            } else {
                bf16x8 z = {0, 0, 0, 0, 0, 0, 0, 0};
                bLo = z; bHi = z;
            }
            unsigned short* gp = g + (long)node * DIM + (lane >> 4) * 4;
#pragma unroll
            for (int t = 0; t < 4; ++t) {
                f32x4 c = {0.f, 0.f, 0.f, 0.f};
                c = __builtin_amdgcn_mfma_f32_16x16x32_bf16(wa[t][0], bLo, c, 0, 0, 0);
                c = __builtin_amdgcn_mfma_f32_16x16x32_bf16(wa[t][1], bHi, c, 0, 0, 0);
                if (node < n_nodes) {
                    union { ushort4 s; __hip_bfloat162 h[2]; } o4;
                    o4.h[0] = __float22bfloat162_rn({c[0], c[1]});
                    o4.h[1] = __float22bfloat162_rn({c[2], c[3]});
                    *(ushort4*)(gp + t * 16) = o4.s;
                }
            }
        }
    }
}

// One block per 64-node slab.  Meta scan, balanced binary-search run copy,
// LDS counting-sort by exact dst (shfl scan), owner-computes gather
// (8-lane groups, uint4 = 8 bf16/lane, unroll 4), + bias.
__global__ void __launch_bounds__(512, 8)
slab_gather(const unsigned short* __restrict__ g,
            const unsigned int* __restrict__ meta,
            const unsigned int* __restrict__ packed,
            const float* __restrict__ b, float* __restrict__ out,
            int n_nodes, int ntiles, int nslab) {
    __shared__ unsigned int raw[SLAB_CAP];
    __shared__ int srt[SLAB_CAP];
    __shared__ int cnt[SLAB_NODES];
    __shared__ int lstarts[SLAB_NODES + 1];
    __shared__ int sc[MAX_TILES];           // inclusive scan of run counts
    __shared__ int runDst[MAX_TILES];
    __shared__ int runSrc[MAX_TILES];
    __shared__ int ceS;
    int tid = threadIdx.x;
    int slab = blockIdx.x;

    // phase 1: read per-tile meta, scan run lengths.
    int c_t = 0, o_t = 0;
    if (tid < ntiles) {
        unsigned int mt = meta[(long)tid * nslab + slab];
        c_t = (int)(mt & 0xFFFFu);
        o_t = (int)(mt >> 16);
    }
    if (tid < MAX_TILES) sc[tid] = c_t;      // zero beyond ntiles (c_t=0)
    __syncthreads();
    for (int off = 1; off < MAX_TILES; off <<= 1) {
        int x = 0;
        if (tid < MAX_TILES && tid >= off) x = sc[tid - off];
        __syncthreads();
        if (tid < MAX_TILES) sc[tid] += x;
        __syncthreads();
    }
    if (tid < ntiles) {
        runDst[tid] = sc[tid] - c_t;         // exclusive
        runSrc[tid] = tid * PART_T + o_t;
    }
    if (tid == 0) ceS = min(sc[MAX_TILES - 1], SLAB_CAP);
    if (tid < SLAB_NODES) cnt[tid] = 0;
    __syncthreads();
    int ce = ceS;

    // phase 2: balanced run copy.  Element k finds its tile by binary
    // search over sc[] (first t with sc[t] > k), then one global read.
    for (int k = tid; k < ce; k += 512) {
        int t = 0;
#pragma unroll
        for (int s = 128; s > 0; s >>= 1) {
            int cand = t + s;
            if (cand <= MAX_TILES - 1 && sc[cand - 1] <= k) t = cand;
        }
        raw[k] = packed[runSrc[t] + (k - runDst[t])];
    }
    __syncthreads();

    // phase 3: counting sort by exact dst-low.
    for (int k = tid; k < ce; k += 512) atomicAdd(&cnt[raw[k] >> 25], 1);
    __syncthreads();
    if (tid < 64) {
        int v = cnt[tid];
        int orig = v;
#pragma unroll
        for (int off = 1; off < 64; off <<= 1) {
            int x = __shfl_up(v, off, 64);
            v += (tid >= off) ? x : 0;
        }
        lstarts[tid + 1] = v;
        cnt[tid] = v - orig;
        if (tid == 0) lstarts[0] = 0;
    }
    __syncthreads();
    for (int k = tid; k < ce; k += 512) {
        unsigned int v = raw[k];
        int nl = (int)(v >> 25);
        int p = atomicAdd(&cnt[nl], 1);
        srt[p] = (int)(v & 0x1FFFFFFu);
    }
    __syncthreads();

    // phase 4: gather + bias + writeout.
    int grp = tid >> 3;      // 0..63: owns node `grp`
    int part = tid & 7;      // uint4 chunk (8 bf16 columns)
    int node0 = slab * SLAB_NODES;
    int nsn = min(SLAB_NODES, n_nodes - node0);
    const uint4* g4 = (const uint4*)g;

    if (grp < nsn) {
        float4 accA = *(const float4*)(b + part * 8);
        float4 accB = *(const float4*)(b + part * 8 + 4);
        int a0 = lstarts[grp], a1 = lstarts[grp + 1];
        int e = a0;
        for (; e + 3 < a1; e += 4) {
            uint4 v0 = g4[(long)srt[e]     * 8 + part];
            uint4 v1 = g4[(long)srt[e + 1] * 8 + part];
            uint4 v2 = g4[(long)srt[e + 2] * 8 + part];
            uint4 v3 = g4[(long)srt[e + 3] * 8 + part];
#define ACC8(v)                                                          \
            accA.x += bf2f((unsigned short)(v.x & 0xFFFF));              \
            accA.y += bf2f((unsigned short)(v.x >> 16));                 \
            accA.z += bf2f((unsigned short)(v.y & 0xFFFF));              \
            accA.w += bf2f((unsigned short)(v.y >> 16));                 \
            accB.x += bf2f((unsigned short)(v.z & 0xFFFF));              \
            accB.y += bf2f((unsigned short)(v.z >> 16));                 \
            accB.z += bf2f((unsigned short)(v.w & 0xFFFF));              \
            accB.w += bf2f((unsigned short)(v.w >> 16));
            ACC8(v0) ACC8(v1) ACC8(v2) ACC8(v3)
        }
        for (; e < a1; ++e) {
            uint4 v0 = g4[(long)srt[e] * 8 + part];
            ACC8(v0)
        }
#undef ACC8
        float* op = out + (long)(node0 + grp) * DIM + part * 8;
        *(float4*)op = accA;
        *(float4*)(op + 4) = accB;
    }
}

extern "C" void kernel_launch(void* const* d_in, const int* in_sizes, int n_in,
                              void* d_out, int out_size, void* d_ws, size_t ws_size,
                              hipStream_t stream) {
    const float* feat = (const float*)d_in[0];
    const int*   src  = (const int*)d_in[1];
    const int*   dst  = (const int*)d_in[2];
    const float* W    = (const float*)d_in[3];
    const float* b    = (const float*)d_in[4];
    float* out = (float*)d_out;

    int n_nodes = in_sizes[0] / DIM;
    int n_edges = in_sizes[1];
    int nslab = (n_nodes + SLAB_NODES - 1) / SLAB_NODES;   // 1563
    int ntiles = (n_edges + PART_T - 1) / PART_T;          // 245

    // workspace: g bf16 (12.8 MB), meta (1.53 MB), packed (4.03 MB)
    char* ws = (char*)d_ws;
    size_t off = 0;
    unsigned short* g = (unsigned short*)(ws + off);
    off += ((size_t)n_nodes * DIM * 2 + 255) & ~(size_t)255;
    unsigned int* meta = (unsigned int*)(ws + off);
    off += ((size_t)ntiles * nslab * 4 + 255) & ~(size_t)255;
    unsigned int* packed = (unsigned int*)(ws + off);      // ntiles*PART_T u32

    int tblocks = (n_nodes + TROWS - 1) / TROWS;           // 196
    prep_kernel<<<ntiles + tblocks, 256, 0, stream>>>(
        feat, W, g, src, dst, meta, packed, n_nodes, n_edges, ntiles);
    slab_gather<<<nslab, 512, 0, stream>>>(g, meta, packed, b, out,
                                           n_nodes, ntiles, nslab);
}